// Round 15
// baseline (271.359 us; speedup 1.0000x reference)
//
#include <hip/hip_runtime.h>

#define IMG_H 512
#define IMG_W 512
#define RPB 16            // rows per block (2 glued 8-row sub-tiles)
#define SUB 8             // rows per sub-tile
#define NROW (SUB + 1)    // 9 (incl. north halo)
#define NLEV 256
#define NB 32
#define NC 3
#define NGRP (NB * NC)    // 96
#define NYB (IMG_H / RPB) // 32
#define BINS (NC * NLEV)  // 768
#define NBLK (NB * NYB)   // 1024
#define NTHR 512
#define NWAVE (NTHR / 64) // 8

// Accumulated per-(b,c,bin) packed {cnt:32|fq:32}: u64 atomics, 192 KB.
// Zero at load; ent phase reads via atomicExch(0) -> self-resetting (replay).
__device__ unsigned long long g_acc[NGRP * NLEV];
__device__ unsigned g_dropA[NGRP];         // dropped frac (i0==255), per (b,c)
__device__ unsigned g_done = 0;            // flush counter (self-resetting)

// fmodf(v+1,2)-1, branch-free, exact.
__device__ __forceinline__ float wrap1(float v) {
    float a = v + 1.0f;
    return a - 2.0f * truncf(0.5f * a) - 1.0f;
}

__device__ __forceinline__ void xform(float& r, float& g, float& bl,
                                      const float* __restrict__ p) {
    float r1 = r + (p[0] * g + p[1] * bl);
    float g1 = g + (p[2] * r1 + p[3] * bl);
    float b1 = bl + (p[4] * r1 + p[5] * g1);
    float r2 = r1 + (p[6] * g1 + p[7] * b1);
    float g2 = g1 + (p[8] * r2 + p[9] * b1);
    float b2 = b1 + (p[10] * r2 + p[11] * g2);
    r = wrap1(r2); g = wrap1(g2); bl = wrap1(b2);
}

// Residual -> ONE packed u32 LDS atomic {count:11|fracQ:21}.
// pred = clip(n+w-nw, min(n,w), max(n,w)) == median(n+w-nw, n, w) -> v_med3_f32.
// JAX wrap: i0 >= -128 always, so j0 = i0 & 255; validity = signed i0 < 256.
// i0==255's frac accumulates in a register (removed from bin 0's pass later).
__device__ __forceinline__ void accum(float y, float n, float w, float nw,
                                      unsigned* __restrict__ h,
                                      unsigned& drop) {
    float pred = __builtin_amdgcn_fmed3f(n + w - nw, n, w);
    float xs = (y - pred + 1.0f) * 127.5f;
    float f = floorf(xs);
    float frac = xs - f;
    int i0 = (int)f;
    unsigned fq = (unsigned)(frac * 1024.0f + 0.5f);
    int j0 = i0 & 255;
    if (i0 < NLEV) {
        atomicAdd(&h[j0], (1u << 21) | fq);
    }
    drop += (i0 == NLEV - 1) ? fq : 0u;
}

__global__ __launch_bounds__(NTHR, 8) void hist_ent(const float* __restrict__ x,
                                                    const float* __restrict__ params,
                                                    float* __restrict__ out) {
    __shared__ unsigned lhw[NWAVE][NC][NLEV];  // 24 KiB packed hists
    __shared__ float bnd[NWAVE][NROW][NC];     // lane-63 odd-col y per wave
    __shared__ unsigned dropw[NC];
    __shared__ unsigned lastFlag;
    const int tid = threadIdx.x;
    const int b = blockIdx.x;
    const int yb = blockIdx.y;
    const int sub = tid >> 8;                  // 0/1: which 8-row sub-tile
    const int stid = tid & 255;                // thread within sub-tile
    const int r0 = yb * RPB + sub * SUB;
    const int wv = tid >> 6;
    const int wvL = wv & 3;                    // wave within sub-tile
    const int lane = tid & 63;

    unsigned* lp = &lhw[0][0][0];
#pragma unroll
    for (int i = tid; i < NWAVE * BINS; i += NTHR) lp[i] = 0u;
    if (tid < NC) dropw[tid] = 0u;

    float p[12];
#pragma unroll
    for (int i = 0; i < 12; ++i) p[i] = params[i];

    const int hw = IMG_H * IMG_W;
    // thread owns cols {2*stid, 2*stid+1}; float2 units
    const float2* base = (const float2*)(x + (size_t)(b * 3) * hw) + stid;

    // Phase A: 27 independent float2 loads
    float a0[NROW], a1[NROW], c0[NROW], c1[NROW], e0[NROW], e1[NROW];
#pragma unroll
    for (int rr = 0; rr < NROW; ++rr) {
        if (rr > 0 || r0 > 0) {
            int ro = (r0 - 1 + rr) * (IMG_W / 2);
            float2 vr = base[ro];
            float2 vg = base[ro + hw / 2];
            float2 vb = base[ro + hw];
            a0[rr] = vr.x; a1[rr] = vr.y;
            c0[rr] = vg.x; c1[rr] = vg.y;
            e0[rr] = vb.x; e1[rr] = vb.y;
        } else {
            a0[rr] = a1[rr] = c0[rr] = c1[rr] = e0[rr] = e1[rr] = 0.0f;
        }
    }

    // Phase B: transform both columns, all rows (transform(0)==0)
#pragma unroll
    for (int rr = 0; rr < NROW; ++rr) {
        xform(a0[rr], c0[rr], e0[rr], p);
        xform(a1[rr], c1[rr], e1[rr], p);
    }

    // boundary: lane 63's odd col feeds next wave's lane 0 (within sub-tile)
    if (lane == 63) {
#pragma unroll
        for (int rr = 0; rr < NROW; ++rr) {
            bnd[wv][rr][0] = a1[rr];
            bnd[wv][rr][1] = c1[rr];
            bnd[wv][rr][2] = e1[rr];
        }
    }
    __syncthreads();

    // stage prev wave's 27 boundary words with ONE ds_read; extract via
    // v_readlane (compile-time lane index) -> zero DS reads in the loop.
    const int pw = (wvL > 0) ? wv - 1 : wv;    // safe index; wvL==0 uses 0.f
    const float* pwb = &bnd[pw][0][0];
    float bv = pwb[lane < NROW * NC ? lane : 0];
    const bool lz = (lane == 0);
    const bool hasL = (wvL > 0);

#define RDL(rr, ch) __int_as_float(__builtin_amdgcn_readlane(__float_as_int(bv), (rr) * NC + (ch)))

    unsigned* h0 = &lhw[wv][0][0];
    unsigned* h1 = &lhw[wv][1][0];
    unsigned* h2 = &lhw[wv][2][0];
    unsigned dr0 = 0u, dr1 = 0u, dr2 = 0u;     // register drop accumulators

    // carries: north (both cols) + northwest (even col; nw of odd = n of even)
    float nA0 = a0[0], nA1 = a1[0];
    float nC0 = c0[0], nC1 = c1[0];
    float nE0 = e0[0], nE1 = e1[0];
    float nwA = __shfl_up(a1[0], 1);
    float nwC = __shfl_up(c1[0], 1);
    float nwE = __shfl_up(e1[0], 1);
    {
        float bA = hasL ? RDL(0, 0) : 0.0f;
        float bC = hasL ? RDL(0, 1) : 0.0f;
        float bE = hasL ? RDL(0, 2) : 0.0f;
        if (lz) { nwA = bA; nwC = bC; nwE = bE; }
    }

#pragma unroll
    for (int rr = 1; rr < NROW; ++rr) {
        float uA0 = a0[rr], uA1 = a1[rr];
        float uC0 = c0[rr], uC1 = c1[rr];
        float uE0 = e0[rr], uE1 = e1[rr];
        float vA = __shfl_up(uA1, 1);
        float vC = __shfl_up(uC1, 1);
        float vE = __shfl_up(uE1, 1);
        float bA = hasL ? RDL(rr, 0) : 0.0f;
        float bC = hasL ? RDL(rr, 1) : 0.0f;
        float bE = hasL ? RDL(rr, 2) : 0.0f;
        if (lz) { vA = bA; vC = bC; vE = bE; }
        // even col: west = vX, nw = nwX ; odd col: west = even cur, nw = even north
        accum(uA0, nA0, vA, nwA, h0, dr0);
        accum(uA1, nA1, uA0, nA0, h0, dr0);
        accum(uC0, nC0, vC, nwC, h1, dr1);
        accum(uC1, nC1, uC0, nC0, h1, dr1);
        accum(uE0, nE0, vE, nwE, h2, dr2);
        accum(uE1, nE1, uE0, nE0, h2, dr2);
        nwA = vA; nA0 = uA0; nA1 = uA1;
        nwC = vC; nC0 = uC0; nC1 = uC1;
        nwE = vE; nE0 = uE0; nE1 = uE1;
    }

    // wave-reduce drops, one LDS add per wave per channel
#pragma unroll
    for (int o = 32; o > 0; o >>= 1) {
        dr0 += __shfl_down(dr0, o);
        dr1 += __shfl_down(dr1, o);
        dr2 += __shfl_down(dr2, o);
    }
    if (lz) {
        atomicAdd(&dropw[0], dr0);
        atomicAdd(&dropw[1], dr1);
        atomicAdd(&dropw[2], dr2);
    }
    __syncthreads();

    // flush: unpack + sum 8 waves, ONE u64 global atomic per bin.
    // Per (b,c,bin): cnt <= 2^18, fq <= 2^28 -> fields never carry.
    const int gb = b * NC;
#pragma unroll
    for (int i = tid; i < BINS; i += NTHR) {
        int c = i >> 8, bin = i & 255;
        unsigned cs = 0, qs = 0;
#pragma unroll
        for (int w2 = 0; w2 < NWAVE; ++w2) {
            unsigned v = lhw[w2][c][bin];
            cs += v >> 21;
            qs += v & 0x1FFFFFu;
        }
        atomicAdd(&g_acc[(gb + c) * NLEV + bin],
                  ((unsigned long long)cs << 32) | (unsigned long long)qs);
    }
    if (tid < NC) atomicAdd(&g_dropA[gb + tid], dropw[tid]);

    // ---- last-block entropy (NO spinning: losers exit immediately) ----
    __threadfence();                           // order my atomics before counter
    __syncthreads();
    if (tid == 0) {
        unsigned prev = atomicAdd(&g_done, 1u);
        lastFlag = (prev == NBLK - 1) ? 1u : 0u;
    }
    __syncthreads();
    if (!lastFlag) return;

    // This block is last: all g_acc finalized. Compute all 96 group
    // entropies in fixed order (deterministic regardless of which block).
    // atomicExch = coherent read + reset-to-zero for the next graph replay.
    __shared__ unsigned fsbL[2][NLEV];
    __shared__ unsigned dshL[2];
    __shared__ float red[NWAVE];
    const int half = tid >> 8;                 // 0/1: which group this iter
    const int bin = tid & 255;
    float acc = 0.0f;
#pragma unroll 1
    for (int it = 0; it < NGRP / 2; ++it) {
        int grp = it * 2 + half;
        unsigned long long v = atomicExch(&g_acc[(size_t)grp * NLEV + bin], 0ull);
        unsigned cnt = (unsigned)(v >> 32);
        unsigned fq  = (unsigned)(v & 0xFFFFFFFFull);
        fsbL[half][bin] = fq;
        if (bin == 0) dshL[half] = atomicExch(&g_dropA[grp], 0u);
        __syncthreads();
        unsigned passq = (bin == 0) ? (fsbL[half][NLEV - 1] - dshL[half])
                                    : fsbL[half][bin - 1];
        float hist = (float)cnt + ((float)passq - (float)fq) * (1.0f / 1024.0f);
        float pr = hist * (1.0f / (float)(IMG_H * IMG_W));
        acc += (pr > 0.0f) ? -pr * log2f(pr) : 0.0f;
        __syncthreads();                       // before fsbL reuse
    }
#pragma unroll
    for (int o = 32; o > 0; o >>= 1) acc += __shfl_down(acc, o);
    if (lane == 0) red[wv] = acc;
    __syncthreads();
    if (tid == 0) {
        float s = 0.0f;
#pragma unroll
        for (int i = 0; i < NWAVE; ++i) s += red[i];
        out[0] = s * (1.0f / (float)NGRP / 8.0f);
        g_done = 0;                            // reset for next replay
    }
}

extern "C" void kernel_launch(void* const* d_in, const int* in_sizes, int n_in,
                              void* d_out, int out_size, void* d_ws, size_t ws_size,
                              hipStream_t stream) {
    const float* x = (const float*)d_in[0];
    const float* params = (const float*)d_in[1];
    float* out = (float*)d_out;

    dim3 grid(NB, NYB);   // 32 x 32
    hist_ent<<<grid, NTHR, 0, stream>>>(x, params, out);
}

// Round 16
// 39.462 us; speedup vs baseline: 6.8765x; 6.8765x over previous
//
#include <hip/hip_runtime.h>

#define IMG_H 512
#define IMG_W 512
#define RPB 16            // rows per block (2 glued 8-row sub-tiles)
#define SUB 8             // rows per sub-tile
#define NROW (SUB + 1)    // 9 (incl. north halo)
#define NLEV 256
#define NB 32
#define NC 3
#define NGRP (NB * NC)    // 96
#define NYB (IMG_H / RPB) // 32
#define BINS (NC * NLEV)  // 768
#define NBLK (NB * NYB)   // 1024
#define NTHR 512
#define NWAVE (NTHR / 64) // 8

// Accumulated per-(b,c,bin) packed {cnt:32|fq:32}: u64 atomics, 192 KB.
// Zero at module load; ent_kernel self-resets after reading (graph replay).
__device__ unsigned long long g_acc[NGRP * NLEV];
__device__ unsigned g_dropA[NGRP];         // dropped frac (i0==255), per (b,c)
__device__ float    g_ent[NGRP];
__device__ unsigned g_done = 0;            // ent-completion counter (self-resetting)

// fmodf(v+1,2)-1, branch-free, exact.
__device__ __forceinline__ float wrap1(float v) {
    float a = v + 1.0f;
    return a - 2.0f * truncf(0.5f * a) - 1.0f;
}

__device__ __forceinline__ void xform(float& r, float& g, float& bl,
                                      const float* __restrict__ p) {
    float r1 = r + (p[0] * g + p[1] * bl);
    float g1 = g + (p[2] * r1 + p[3] * bl);
    float b1 = bl + (p[4] * r1 + p[5] * g1);
    float r2 = r1 + (p[6] * g1 + p[7] * b1);
    float g2 = g1 + (p[8] * r2 + p[9] * b1);
    float b2 = b1 + (p[10] * r2 + p[11] * g2);
    r = wrap1(r2); g = wrap1(g2); bl = wrap1(b2);
}

// Residual -> ONE packed u32 LDS atomic {count:11|fracQ:21}.
// pred = clip(n+w-nw, min(n,w), max(n,w)) == median(n+w-nw, n, w) -> v_med3_f32
// (exact: all inputs finite, no NaN). JAX wrap: i0 >= -128 always, so
// j0 = i0 & 255; validity = signed i0 < 256 (negatives valid after wrap).
// i0==255's frac accumulates in a register (removed from bin 0's pass later).
__device__ __forceinline__ void accum(float y, float n, float w, float nw,
                                      unsigned* __restrict__ h,
                                      unsigned& drop) {
    float pred = __builtin_amdgcn_fmed3f(n + w - nw, n, w);
    float xs = (y - pred + 1.0f) * 127.5f;
    float f = floorf(xs);
    float frac = xs - f;
    int i0 = (int)f;
    unsigned fq = (unsigned)(frac * 1024.0f + 0.5f);
    int j0 = i0 & 255;
    if (i0 < NLEV) {
        atomicAdd(&h[j0], (1u << 21) | fq);
    }
    drop += (i0 == NLEV - 1) ? fq : 0u;
}

__global__ __launch_bounds__(NTHR) void hist_kernel(const float* __restrict__ x,
                                                    const float* __restrict__ params) {
    __shared__ unsigned lhw[NWAVE][NC][NLEV];  // 24 KiB packed hists
    __shared__ float bnd[NWAVE][NROW][NC];     // lane-63 odd-col y per wave
    __shared__ unsigned dropw[NC];
    const int tid = threadIdx.x;
    const int b = blockIdx.x;
    const int yb = blockIdx.y;
    const int sub = tid >> 8;                  // 0/1: which 8-row sub-tile
    const int stid = tid & 255;                // thread within sub-tile
    const int r0 = yb * RPB + sub * SUB;
    const int wv = tid >> 6;
    const int wvL = wv & 3;                    // wave within sub-tile
    const int lane = tid & 63;

    unsigned* lp = &lhw[0][0][0];
#pragma unroll
    for (int i = tid; i < NWAVE * BINS; i += NTHR) lp[i] = 0u;
    if (tid < NC) dropw[tid] = 0u;

    float p[12];
#pragma unroll
    for (int i = 0; i < 12; ++i) p[i] = params[i];

    const int hw = IMG_H * IMG_W;
    // thread owns cols {2*stid, 2*stid+1}; float2 units
    const float2* base = (const float2*)(x + (size_t)(b * 3) * hw) + stid;

    // Phase A: 27 independent float2 loads
    float a0[NROW], a1[NROW], c0[NROW], c1[NROW], e0[NROW], e1[NROW];
#pragma unroll
    for (int rr = 0; rr < NROW; ++rr) {
        if (rr > 0 || r0 > 0) {
            int ro = (r0 - 1 + rr) * (IMG_W / 2);
            float2 vr = base[ro];
            float2 vg = base[ro + hw / 2];
            float2 vb = base[ro + hw];
            a0[rr] = vr.x; a1[rr] = vr.y;
            c0[rr] = vg.x; c1[rr] = vg.y;
            e0[rr] = vb.x; e1[rr] = vb.y;
        } else {
            a0[rr] = a1[rr] = c0[rr] = c1[rr] = e0[rr] = e1[rr] = 0.0f;
        }
    }

    // Phase B: transform both columns, all rows (transform(0)==0)
#pragma unroll
    for (int rr = 0; rr < NROW; ++rr) {
        xform(a0[rr], c0[rr], e0[rr], p);
        xform(a1[rr], c1[rr], e1[rr], p);
    }

    // boundary: lane 63's odd col feeds next wave's lane 0 (within sub-tile)
    if (lane == 63) {
#pragma unroll
        for (int rr = 0; rr < NROW; ++rr) {
            bnd[wv][rr][0] = a1[rr];
            bnd[wv][rr][1] = c1[rr];
            bnd[wv][rr][2] = e1[rr];
        }
    }
    __syncthreads();

    // stage prev wave's 27 boundary words with ONE ds_read; extract via
    // v_readlane (compile-time lane index) -> zero DS reads in the loop.
    const int pw = (wvL > 0) ? wv - 1 : wv;    // safe index; wvL==0 uses 0.f
    const float* pwb = &bnd[pw][0][0];
    float bv = pwb[lane < NROW * NC ? lane : 0];
    const bool lz = (lane == 0);
    const bool hasL = (wvL > 0);

#define RDL(rr, ch) __int_as_float(__builtin_amdgcn_readlane(__float_as_int(bv), (rr) * NC + (ch)))

    unsigned* h0 = &lhw[wv][0][0];
    unsigned* h1 = &lhw[wv][1][0];
    unsigned* h2 = &lhw[wv][2][0];
    unsigned dr0 = 0u, dr1 = 0u, dr2 = 0u;     // register drop accumulators

    // carries: north (both cols) + northwest (even col; nw of odd = n of even)
    float nA0 = a0[0], nA1 = a1[0];
    float nC0 = c0[0], nC1 = c1[0];
    float nE0 = e0[0], nE1 = e1[0];
    float nwA = __shfl_up(a1[0], 1);
    float nwC = __shfl_up(c1[0], 1);
    float nwE = __shfl_up(e1[0], 1);
    {
        float bA = hasL ? RDL(0, 0) : 0.0f;
        float bC = hasL ? RDL(0, 1) : 0.0f;
        float bE = hasL ? RDL(0, 2) : 0.0f;
        if (lz) { nwA = bA; nwC = bC; nwE = bE; }
    }

#pragma unroll
    for (int rr = 1; rr < NROW; ++rr) {
        float uA0 = a0[rr], uA1 = a1[rr];
        float uC0 = c0[rr], uC1 = c1[rr];
        float uE0 = e0[rr], uE1 = e1[rr];
        float vA = __shfl_up(uA1, 1);
        float vC = __shfl_up(uC1, 1);
        float vE = __shfl_up(uE1, 1);
        float bA = hasL ? RDL(rr, 0) : 0.0f;
        float bC = hasL ? RDL(rr, 1) : 0.0f;
        float bE = hasL ? RDL(rr, 2) : 0.0f;
        if (lz) { vA = bA; vC = bC; vE = bE; }
        // even col: west = vX, nw = nwX ; odd col: west = even cur, nw = even north
        accum(uA0, nA0, vA, nwA, h0, dr0);
        accum(uA1, nA1, uA0, nA0, h0, dr0);
        accum(uC0, nC0, vC, nwC, h1, dr1);
        accum(uC1, nC1, uC0, nC0, h1, dr1);
        accum(uE0, nE0, vE, nwE, h2, dr2);
        accum(uE1, nE1, uE0, nE0, h2, dr2);
        nwA = vA; nA0 = uA0; nA1 = uA1;
        nwC = vC; nC0 = uC0; nC1 = uC1;
        nwE = vE; nE0 = uE0; nE1 = uE1;
    }

    // wave-reduce drops, one LDS add per wave per channel
#pragma unroll
    for (int o = 32; o > 0; o >>= 1) {
        dr0 += __shfl_down(dr0, o);
        dr1 += __shfl_down(dr1, o);
        dr2 += __shfl_down(dr2, o);
    }
    if (lz) {
        atomicAdd(&dropw[0], dr0);
        atomicAdd(&dropw[1], dr1);
        atomicAdd(&dropw[2], dr2);
    }
    __syncthreads();

    // flush: unpack + sum 8 waves, ONE u64 global atomic per bin.
    // Per (b,c,bin): cnt <= 2^18, fq <= 2^28 -> fields never carry.
    const int gb = b * NC;
#pragma unroll
    for (int i = tid; i < BINS; i += NTHR) {
        int c = i >> 8, bin = i & 255;
        unsigned cs = 0, qs = 0;
#pragma unroll
        for (int w2 = 0; w2 < NWAVE; ++w2) {
            unsigned v = lhw[w2][c][bin];
            cs += v >> 21;
            qs += v & 0x1FFFFFu;
        }
        atomicAdd(&g_acc[(gb + c) * NLEV + bin],
                  ((unsigned long long)cs << 32) | (unsigned long long)qs);
    }
    if (tid < NC) atomicAdd(&g_dropA[gb + tid], dropw[tid]);
}

// Entropy: one block per (b,c); thread t owns bin t. Read accumulated
// {cnt,fq}, self-reset to zero (one reader per slot -> safe, deterministic,
// keeps g_acc==0 invariant for graph replays).
__global__ __launch_bounds__(256) void ent_kernel(float* __restrict__ out) {
    const int g = blockIdx.x;          // b*NC + c
    const int t = threadIdx.x;         // bin
    unsigned long long v = g_acc[(size_t)g * NLEV + t];
    g_acc[(size_t)g * NLEV + t] = 0ull;
    unsigned cnt = (unsigned)(v >> 32);
    unsigned fq  = (unsigned)(v & 0xFFFFFFFFull);
    __shared__ unsigned fsb[NLEV];
    __shared__ unsigned dsh;
    fsb[t] = fq;
    if (t == 0) { dsh = g_dropA[g]; g_dropA[g] = 0u; }
    __syncthreads();
    // pass-in from previous bin; bin 0 receives bin 255's frac minus dropped
    unsigned passq = (t == 0) ? (fsb[NLEV - 1] - dsh) : fsb[t - 1];
    float hist = (float)cnt + ((float)passq - (float)fq) * (1.0f / 1024.0f);
    float pr = hist * (1.0f / (float)(IMG_H * IMG_W));
    float term = (pr > 0.0f) ? -pr * log2f(pr) : 0.0f;
#pragma unroll
    for (int o = 32; o > 0; o >>= 1) term += __shfl_down(term, o);
    __shared__ float red[4];
    if ((t & 63) == 0) red[t >> 6] = term;
    __syncthreads();
    if (t == 0) {
        g_ent[g] = red[0] + red[1] + red[2] + red[3];
        __threadfence();                            // release g_ent
        unsigned prev = atomicAdd(&g_done, 1u);
        if (prev == NGRP - 1) {                     // last ent block finishes
            __threadfence();                        // acquire g_ent
            float s = 0.0f;
            for (int i = 0; i < NGRP; ++i) s += g_ent[i];   // fixed order
            out[0] = s * (1.0f / (float)NGRP / 8.0f);
            g_done = 0;                             // reset for next replay
        }
    }
}

extern "C" void kernel_launch(void* const* d_in, const int* in_sizes, int n_in,
                              void* d_out, int out_size, void* d_ws, size_t ws_size,
                              hipStream_t stream) {
    const float* x = (const float*)d_in[0];
    const float* params = (const float*)d_in[1];
    float* out = (float*)d_out;

    dim3 grid(NB, NYB);   // 32 x 32
    hist_kernel<<<grid, NTHR, 0, stream>>>(x, params);
    ent_kernel<<<NGRP, 256, 0, stream>>>(out);
}

// Round 17
// 39.240 us; speedup vs baseline: 6.9154x; 1.0057x over previous
//
#include <hip/hip_runtime.h>

#define IMG_H 512
#define IMG_W 512
#define RPB 16            // rows per block (2 glued 8-row sub-tiles)
#define SUB 8             // rows per sub-tile
#define NROW (SUB + 1)    // 9 (incl. north halo)
#define NLEV 256
#define NB 32
#define NC 3
#define NGRP (NB * NC)    // 96
#define NYB (IMG_H / RPB) // 32
#define BINS (NC * NLEV)  // 768
#define NBLK (NB * NYB)   // 1024
#define NTHR 512
#define NWAVE (NTHR / 64) // 8

// Accumulated per-(b,c,bin) packed {cnt:32|fq:32}: u64 atomics, 192 KB.
// Zero at module load; ent_kernel self-resets after reading (graph replay).
__device__ unsigned long long g_acc[NGRP * NLEV];
__device__ unsigned g_dropA[NGRP];         // dropped frac (i0==255), per (b,c)
__device__ float    g_ent[NGRP];
__device__ unsigned g_done = 0;            // ent-completion counter (self-resetting)

// fmodf(v+1,2)-1, branch-free, exact.
__device__ __forceinline__ float wrap1(float v) {
    float a = v + 1.0f;
    return a - 2.0f * truncf(0.5f * a) - 1.0f;
}

// Full-wave shift-up-by-1 via DPP wave_shr1 (0x138): single VALU mov on the
// vector pipe, NO ds_bpermute -> frees the LDS pipe for the histogram atomics.
// Lane 0 keeps its own value (bound_ctrl=false, old=src) -- caller overwrites
// lane 0 via the boundary readlane/cndmask fixup anyway.
__device__ __forceinline__ float shfl_up1(float v) {
    int i = __float_as_int(v);
    int r = __builtin_amdgcn_update_dpp(i, i, 0x138, 0xF, 0xF, false);
    return __int_as_float(r);
}

__device__ __forceinline__ void xform(float& r, float& g, float& bl,
                                      const float* __restrict__ p) {
    float r1 = r + (p[0] * g + p[1] * bl);
    float g1 = g + (p[2] * r1 + p[3] * bl);
    float b1 = bl + (p[4] * r1 + p[5] * g1);
    float r2 = r1 + (p[6] * g1 + p[7] * b1);
    float g2 = g1 + (p[8] * r2 + p[9] * b1);
    float b2 = b1 + (p[10] * r2 + p[11] * g2);
    r = wrap1(r2); g = wrap1(g2); bl = wrap1(b2);
}

// Residual -> ONE packed u32 LDS atomic {count:11|fracQ:21}.
// pred = clip(n+w-nw, min(n,w), max(n,w)) == median(n+w-nw, n, w) -> v_med3_f32
// (exact: all inputs finite, no NaN). JAX wrap: i0 >= -128 always, so
// j0 = i0 & 255; validity = signed i0 < 256 (negatives valid after wrap).
// i0==255's frac accumulates in a register (removed from bin 0's pass later).
__device__ __forceinline__ void accum(float y, float n, float w, float nw,
                                      unsigned* __restrict__ h,
                                      unsigned& drop) {
    float pred = __builtin_amdgcn_fmed3f(n + w - nw, n, w);
    float xs = (y - pred + 1.0f) * 127.5f;
    float f = floorf(xs);
    float frac = xs - f;
    int i0 = (int)f;
    unsigned fq = (unsigned)(frac * 1024.0f + 0.5f);
    int j0 = i0 & 255;
    if (i0 < NLEV) {
        atomicAdd(&h[j0], (1u << 21) | fq);
    }
    drop += (i0 == NLEV - 1) ? fq : 0u;
}

__global__ __launch_bounds__(NTHR) void hist_kernel(const float* __restrict__ x,
                                                    const float* __restrict__ params) {
    __shared__ unsigned lhw[NWAVE][NC][NLEV];  // 24 KiB packed hists
    __shared__ float bnd[NWAVE][NROW][NC];     // lane-63 odd-col y per wave
    __shared__ unsigned dropw[NC];
    const int tid = threadIdx.x;
    const int b = blockIdx.x;
    const int yb = blockIdx.y;
    const int sub = tid >> 8;                  // 0/1: which 8-row sub-tile
    const int stid = tid & 255;                // thread within sub-tile
    const int r0 = yb * RPB + sub * SUB;
    const int wv = tid >> 6;
    const int wvL = wv & 3;                    // wave within sub-tile
    const int lane = tid & 63;

    unsigned* lp = &lhw[0][0][0];
#pragma unroll
    for (int i = tid; i < NWAVE * BINS; i += NTHR) lp[i] = 0u;
    if (tid < NC) dropw[tid] = 0u;

    float p[12];
#pragma unroll
    for (int i = 0; i < 12; ++i) p[i] = params[i];

    const int hw = IMG_H * IMG_W;
    // thread owns cols {2*stid, 2*stid+1}; float2 units
    const float2* base = (const float2*)(x + (size_t)(b * 3) * hw) + stid;

    // Phase A: 27 independent float2 loads
    float a0[NROW], a1[NROW], c0[NROW], c1[NROW], e0[NROW], e1[NROW];
#pragma unroll
    for (int rr = 0; rr < NROW; ++rr) {
        if (rr > 0 || r0 > 0) {
            int ro = (r0 - 1 + rr) * (IMG_W / 2);
            float2 vr = base[ro];
            float2 vg = base[ro + hw / 2];
            float2 vb = base[ro + hw];
            a0[rr] = vr.x; a1[rr] = vr.y;
            c0[rr] = vg.x; c1[rr] = vg.y;
            e0[rr] = vb.x; e1[rr] = vb.y;
        } else {
            a0[rr] = a1[rr] = c0[rr] = c1[rr] = e0[rr] = e1[rr] = 0.0f;
        }
    }

    // Phase B: transform both columns, all rows (transform(0)==0)
#pragma unroll
    for (int rr = 0; rr < NROW; ++rr) {
        xform(a0[rr], c0[rr], e0[rr], p);
        xform(a1[rr], c1[rr], e1[rr], p);
    }

    // boundary: lane 63's odd col feeds next wave's lane 0 (within sub-tile)
    if (lane == 63) {
#pragma unroll
        for (int rr = 0; rr < NROW; ++rr) {
            bnd[wv][rr][0] = a1[rr];
            bnd[wv][rr][1] = c1[rr];
            bnd[wv][rr][2] = e1[rr];
        }
    }
    __syncthreads();

    // stage prev wave's 27 boundary words with ONE ds_read; extract via
    // v_readlane (compile-time lane index) -> zero DS reads in the loop.
    const int pw = (wvL > 0) ? wv - 1 : wv;    // safe index; wvL==0 uses 0.f
    const float* pwb = &bnd[pw][0][0];
    float bv = pwb[lane < NROW * NC ? lane : 0];
    const bool lz = (lane == 0);
    const bool hasL = (wvL > 0);

#define RDL(rr, ch) __int_as_float(__builtin_amdgcn_readlane(__float_as_int(bv), (rr) * NC + (ch)))

    unsigned* h0 = &lhw[wv][0][0];
    unsigned* h1 = &lhw[wv][1][0];
    unsigned* h2 = &lhw[wv][2][0];
    unsigned dr0 = 0u, dr1 = 0u, dr2 = 0u;     // register drop accumulators

    // carries: north (both cols) + northwest (even col; nw of odd = n of even)
    float nA0 = a0[0], nA1 = a1[0];
    float nC0 = c0[0], nC1 = c1[0];
    float nE0 = e0[0], nE1 = e1[0];
    float nwA = shfl_up1(a1[0]);
    float nwC = shfl_up1(c1[0]);
    float nwE = shfl_up1(e1[0]);
    {
        float bA = hasL ? RDL(0, 0) : 0.0f;
        float bC = hasL ? RDL(0, 1) : 0.0f;
        float bE = hasL ? RDL(0, 2) : 0.0f;
        if (lz) { nwA = bA; nwC = bC; nwE = bE; }
    }

#pragma unroll
    for (int rr = 1; rr < NROW; ++rr) {
        float uA0 = a0[rr], uA1 = a1[rr];
        float uC0 = c0[rr], uC1 = c1[rr];
        float uE0 = e0[rr], uE1 = e1[rr];
        float vA = shfl_up1(uA1);
        float vC = shfl_up1(uC1);
        float vE = shfl_up1(uE1);
        float bA = hasL ? RDL(rr, 0) : 0.0f;
        float bC = hasL ? RDL(rr, 1) : 0.0f;
        float bE = hasL ? RDL(rr, 2) : 0.0f;
        if (lz) { vA = bA; vC = bC; vE = bE; }
        // even col: west = vX, nw = nwX ; odd col: west = even cur, nw = even north
        accum(uA0, nA0, vA, nwA, h0, dr0);
        accum(uA1, nA1, uA0, nA0, h0, dr0);
        accum(uC0, nC0, vC, nwC, h1, dr1);
        accum(uC1, nC1, uC0, nC0, h1, dr1);
        accum(uE0, nE0, vE, nwE, h2, dr2);
        accum(uE1, nE1, uE0, nE0, h2, dr2);
        nwA = vA; nA0 = uA0; nA1 = uA1;
        nwC = vC; nC0 = uC0; nC1 = uC1;
        nwE = vE; nE0 = uE0; nE1 = uE1;
    }

    // wave-reduce drops, one LDS add per wave per channel
#pragma unroll
    for (int o = 32; o > 0; o >>= 1) {
        dr0 += __shfl_down(dr0, o);
        dr1 += __shfl_down(dr1, o);
        dr2 += __shfl_down(dr2, o);
    }
    if (lz) {
        atomicAdd(&dropw[0], dr0);
        atomicAdd(&dropw[1], dr1);
        atomicAdd(&dropw[2], dr2);
    }
    __syncthreads();

    // flush: unpack + sum 8 waves, ONE u64 global atomic per bin.
    // Per (b,c,bin): cnt <= 2^18, fq <= 2^28 -> fields never carry.
    const int gb = b * NC;
#pragma unroll
    for (int i = tid; i < BINS; i += NTHR) {
        int c = i >> 8, bin = i & 255;
        unsigned cs = 0, qs = 0;
#pragma unroll
        for (int w2 = 0; w2 < NWAVE; ++w2) {
            unsigned v = lhw[w2][c][bin];
            cs += v >> 21;
            qs += v & 0x1FFFFFu;
        }
        atomicAdd(&g_acc[(gb + c) * NLEV + bin],
                  ((unsigned long long)cs << 32) | (unsigned long long)qs);
    }
    if (tid < NC) atomicAdd(&g_dropA[gb + tid], dropw[tid]);
}

// Entropy: one block per (b,c); thread t owns bin t. Read accumulated
// {cnt,fq}, self-reset to zero (one reader per slot -> safe, deterministic,
// keeps g_acc==0 invariant for graph replays).
__global__ __launch_bounds__(256) void ent_kernel(float* __restrict__ out) {
    const int g = blockIdx.x;          // b*NC + c
    const int t = threadIdx.x;         // bin
    unsigned long long v = g_acc[(size_t)g * NLEV + t];
    g_acc[(size_t)g * NLEV + t] = 0ull;
    unsigned cnt = (unsigned)(v >> 32);
    unsigned fq  = (unsigned)(v & 0xFFFFFFFFull);
    __shared__ unsigned fsb[NLEV];
    __shared__ unsigned dsh;
    fsb[t] = fq;
    if (t == 0) { dsh = g_dropA[g]; g_dropA[g] = 0u; }
    __syncthreads();
    // pass-in from previous bin; bin 0 receives bin 255's frac minus dropped
    unsigned passq = (t == 0) ? (fsb[NLEV - 1] - dsh) : fsb[t - 1];
    float hist = (float)cnt + ((float)passq - (float)fq) * (1.0f / 1024.0f);
    float pr = hist * (1.0f / (float)(IMG_H * IMG_W));
    float term = (pr > 0.0f) ? -pr * log2f(pr) : 0.0f;
#pragma unroll
    for (int o = 32; o > 0; o >>= 1) term += __shfl_down(term, o);
    __shared__ float red[4];
    if ((t & 63) == 0) red[t >> 6] = term;
    __syncthreads();
    if (t == 0) {
        g_ent[g] = red[0] + red[1] + red[2] + red[3];
        __threadfence();                            // release g_ent
        unsigned prev = atomicAdd(&g_done, 1u);
        if (prev == NGRP - 1) {                     // last ent block finishes
            __threadfence();                        // acquire g_ent
            float s = 0.0f;
            for (int i = 0; i < NGRP; ++i) s += g_ent[i];   // fixed order
            out[0] = s * (1.0f / (float)NGRP / 8.0f);
            g_done = 0;                             // reset for next replay
        }
    }
}

extern "C" void kernel_launch(void* const* d_in, const int* in_sizes, int n_in,
                              void* d_out, int out_size, void* d_ws, size_t ws_size,
                              hipStream_t stream) {
    const float* x = (const float*)d_in[0];
    const float* params = (const float*)d_in[1];
    float* out = (float*)d_out;

    dim3 grid(NB, NYB);   // 32 x 32
    hist_kernel<<<grid, NTHR, 0, stream>>>(x, params);
    ent_kernel<<<NGRP, 256, 0, stream>>>(out);
}